// Round 5
// baseline (2435.587 us; speedup 1.0000x reference)
//
#include <hip/hip_runtime.h>

// LSTM: B=256, T=512, I=64, H=512, G=4H=2048.
// gates = W @ [h; x], W = [R | kernel^T], K = 576.
// Persistent kernel: 128 WGs x 512 threads = 16 batch-groups x 8 WGs.
// W register-resident (144 regs/lane), c in regs.
// h exchange: TAGGED dwords ((s<<16)|bf16h) stored with relaxed agent-scope
// atomics, double-buffered by step parity. The poll IS the data load: one
// fabric round-trip per step. No flags, no fences, no hand-rolled sc bits.
#define TSTEPS 512
#define BATCH  256
#define ISZ    64
#define HSZ    512
#define GSZ    2048
#define NKT    18
#define BG     16

typedef __attribute__((ext_vector_type(8))) short short8;
typedef __attribute__((ext_vector_type(4))) float f32x4;
typedef __attribute__((ext_vector_type(4))) unsigned int u32x4;

static __device__ __forceinline__ unsigned short f2bf(float f) {
    unsigned int u = __float_as_uint(f);
    return (unsigned short)((u + 0x7fffu + ((u >> 16) & 1u)) >> 16);  // RNE
}
static __device__ __forceinline__ float sig_(float x) {
    return 1.0f / (1.0f + __expf(-x));
}
static __device__ __forceinline__ float tanh_(float x) {
    float e = __expf(-2.0f * fabsf(x));
    float t = (1.0f - e) / (1.0f + e);
    return copysignf(t, x);
}

// Pack W = [R | kernel^T] (fp32) into bf16 MFMA A-fragment order.
// Frag t = ((jj*8 + m)*18 + kt)*64 + lane; row r = 16m + (lane&15);
// gate q = r&3; hco = r>>2; global row = q*512 + jj*32 + hco.
__global__ void pack_w(const float* __restrict__ R, const float* __restrict__ Kin,
                       unsigned short* __restrict__ wpack)
{
    const int t  = blockIdx.x * 256 + threadIdx.x;
    const int l  = t & 63;
    const int kt = (t >> 6) % NKT;
    const int m  = (t / (64 * NKT)) & 7;
    const int jj = t / (64 * NKT * 8);
    const int r   = 16 * m + (l & 15);
    const int q   = r & 3;
    const int hco = r >> 2;
    const int grow  = q * HSZ + jj * 32 + hco;
    const int kbase = kt * 32 + (l >> 4) * 8;
    unsigned int pk[4];
#pragma unroll
    for (int p = 0; p < 4; ++p) {
        const int k0 = kbase + 2 * p;
        const int k1 = k0 + 1;
        const float f0 = (k0 < HSZ) ? R[(size_t)grow * HSZ + k0]
                                    : Kin[(size_t)(k0 - HSZ) * GSZ + grow];
        const float f1 = (k1 < HSZ) ? R[(size_t)grow * HSZ + k1]
                                    : Kin[(size_t)(k1 - HSZ) * GSZ + grow];
        pk[p] = (unsigned)f2bf(f0) | ((unsigned)f2bf(f1) << 16);
    }
    uint4 v = make_uint4(pk[0], pk[1], pk[2], pk[3]);
    *reinterpret_cast<uint4*>(wpack + (size_t)t * 8) = v;
}

// Zero the tagged h buffer (tags=0 never match any step >= 1). Runs every
// launch -> graph-replay safe.
__global__ void zero_tags(u32x4* __restrict__ hb) {
    u32x4 z = {0u, 0u, 0u, 0u};
    hb[blockIdx.x * 256 + threadIdx.x] = z;
}

__global__ __launch_bounds__(512, 2) void lstm_persist(
    const unsigned short* __restrict__ wpack,
    const float* __restrict__ input_seq,
    const float* __restrict__ bias,
    unsigned int* __restrict__ hbuf,     // [2][BATCH][HSZ] tagged dwords
    float* __restrict__ hlast)
{
    __shared__ __align__(16) unsigned short lds_B[16][584];   // [batch][k]
    __shared__ __align__(16) unsigned short lds_hn[16][68];   // new-h staging
    const int tid = threadIdx.x;
    const int bid = blockIdx.x;
    const int gi = (bid & 7) + 8 * (bid >> 6);   // batch-group
    const int jw = (bid >> 3) & 7;               // h-col window [jw*64, +64)

    const int w  = tid >> 6;
    const int l  = tid & 63;
    const int bb = l & 15;
    const int lg = l >> 4;
    const int jj = 2 * jw + (w >> 2);
    const int mw = w & 3;
    const int m0 = 2 * mw, m1 = 2 * mw + 1;

    // ---- one-time: W fragments into registers ----
    short8 wA[NKT], wB[NKT];
#pragma unroll
    for (int kt = 0; kt < NKT; ++kt) {
        wA[kt] = *reinterpret_cast<const short8*>(
            wpack + (((size_t)(jj * 8 + m0) * NKT + kt) * 64 + l) * 8);
        wB[kt] = *reinterpret_cast<const short8*>(
            wpack + (((size_t)(jj * 8 + m1) * NKT + kt) * 64 + l) * 8);
    }
    const int hc0 = 4 * m0 + lg, hc1 = 4 * m1 + lg;
    const int gh0 = jj * 32 + hc0, gh1 = jj * 32 + hc1;
    float bs0[4], bs1[4];
#pragma unroll
    for (int qg = 0; qg < 4; ++qg) {
        bs0[qg] = bias[qg * HSZ + gh0];
        bs1[qg] = bias[qg * HSZ + gh1];
    }

    float c0 = 0.f, c1 = 0.f;

    // consumer mapping: thread (sb, sc) stages batch sb, cols [sc*16, +16)
    const int sb = tid & 15, sc = tid >> 4;
    const float* xbase = input_seq + (size_t)(gi * BG + sb) * (TSTEPS * ISZ) + sc * 2;
    float2 xr = *reinterpret_cast<const float2*>(xbase);

    unsigned long long* const hb0 = reinterpret_cast<unsigned long long*>(hbuf);
    unsigned long long* const hb1 =
        reinterpret_cast<unsigned long long*>(hbuf + (size_t)BATCH * HSZ);
    const size_t csrc = ((size_t)(gi * BG + sb) * HSZ + sc * 16) >> 1;  // u64 idx
    // producer mapping: thread (b_, pr) stores batch b_, cols jw*64+pr*2 (+1)
    const int b_ = tid >> 5, pr = tid & 31;
    const size_t pdst = ((size_t)(gi * BG + b_) * HSZ + jw * 64 + pr * 2) >> 1;

    for (int s = 0; s < TSTEPS; ++s) {
        // ---- acquire h(s): poll tagged data (poll IS the load) ----
        if (s > 0) {
            const unsigned long long* src = ((s & 1) ? hb1 : hb0) + csrc;
            const unsigned long long want =
                ((unsigned long long)s << 48) | ((unsigned long long)s << 16);
            unsigned long long v[8];
            bool ok;
            do {
                ok = true;
#pragma unroll
                for (int i = 0; i < 8; ++i)
                    v[i] = __hip_atomic_load(src + i, __ATOMIC_RELAXED,
                                             __HIP_MEMORY_SCOPE_AGENT);
#pragma unroll
                for (int i = 0; i < 8; ++i)
                    ok = ok && ((v[i] & 0xFFFF0000FFFF0000ull) == want);
            } while (!ok);
            unsigned d[8];
#pragma unroll
            for (int i = 0; i < 8; ++i)
                d[i] = (unsigned)(v[i] & 0xFFFFu) |
                       ((unsigned)(v[i] >> 16) & 0xFFFF0000u);
            u32x4* dst = reinterpret_cast<u32x4*>(&lds_B[sb][sc * 16]);
            u32x4 lo = {d[0], d[1], d[2], d[3]};
            u32x4 hi = {d[4], d[5], d[6], d[7]};
            dst[0] = lo; dst[1] = hi;
        } else {
            u32x4 z = {0u, 0u, 0u, 0u};
            u32x4* dst = reinterpret_cast<u32x4*>(&lds_B[sb][sc * 16]);
            dst[0] = z; dst[1] = z;
        }
        // stage x(s); prefetch x(s+1)
        {
            unsigned px = (unsigned)f2bf(xr.x) | ((unsigned)f2bf(xr.y) << 16);
            *reinterpret_cast<unsigned*>(&lds_B[sb][HSZ + sc * 2]) = px;
            if (s + 1 < TSTEPS)
                xr = *reinterpret_cast<const float2*>(xbase + (size_t)(s + 1) * ISZ);
        }
        __syncthreads();   // B: staging complete

        f32x4 acc0 = {0.f, 0.f, 0.f, 0.f};
        f32x4 acc1 = {0.f, 0.f, 0.f, 0.f};
#pragma unroll
        for (int kt = 0; kt < NKT; ++kt) {
            const short8 bf = *reinterpret_cast<const short8*>(
                &lds_B[bb][kt * 32 + lg * 8]);
            acc0 = __builtin_amdgcn_mfma_f32_16x16x32_bf16(wA[kt], bf, acc0, 0, 0, 0);
            acc1 = __builtin_amdgcn_mfma_f32_16x16x32_bf16(wB[kt], bf, acc1, 0, 0, 0);
        }

        // ---- lane-local cell update ----
        const float fg0 = sig_(acc0[0] + bs0[0]);
        const float ig0 = sig_(acc0[1] + bs0[1]);
        const float cp0 = tanh_(acc0[2] + bs0[2]);
        const float og0 = sig_(acc0[3] + bs0[3]);
        c0 = fg0 * c0 + ig0 * cp0;
        const float h0v = og0 * tanh_(c0);
        const float fg1 = sig_(acc1[0] + bs1[0]);
        const float ig1 = sig_(acc1[1] + bs1[1]);
        const float cp1 = tanh_(acc1[2] + bs1[2]);
        const float og1 = sig_(acc1[3] + bs1[3]);
        c1 = fg1 * c1 + ig1 * cp1;
        const float h1v = og1 * tanh_(c1);

        if (s == TSTEPS - 1) {
            hlast[(size_t)(gi * BG + bb) * HSZ + gh0] = h0v;
            hlast[(size_t)(gi * BG + bb) * HSZ + gh1] = h1v;
            break;
        }
        // stage new h into LDS (WG col window [jw*64, +64))
        const int cw = (w >> 2) * 32;
        lds_hn[bb][cw + hc0] = f2bf(h0v);
        lds_hn[bb][cw + hc1] = f2bf(h1v);
        __syncthreads();   // C: lds_hn ready; lds_B MFMA reads done

        // ---- publish h(s+1): coalesced tagged u64 atomic stores, no drain ----
        {
            const unsigned h2 = *reinterpret_cast<const unsigned*>(&lds_hn[b_][pr * 2]);
            const unsigned t16 = (unsigned)(s + 1) << 16;
            const unsigned lo = (h2 & 0xFFFFu) | t16;
            const unsigned hi = (h2 >> 16) | t16;
            const unsigned long long tagged =
                ((unsigned long long)hi << 32) | (unsigned long long)lo;
            unsigned long long* dst = (((s + 1) & 1) ? hb1 : hb0) + pdst;
            __hip_atomic_store(dst, tagged, __ATOMIC_RELAXED,
                               __HIP_MEMORY_SCOPE_AGENT);
        }
    }
}

// out[b] = h_last[b,:] . Wout + bout
__global__ void out_kernel(const float* __restrict__ hlast,
                           const float* __restrict__ wout,
                           const float* __restrict__ bout,
                           float* __restrict__ out)
{
    const int b = blockIdx.x;
    const int l = threadIdx.x;
    float p = 0.f;
    for (int k = l; k < HSZ; k += 64)
        p += hlast[(size_t)b * HSZ + k] * wout[k];
    for (int off = 32; off > 0; off >>= 1)
        p += __shfl_down(p, off, 64);
    if (l == 0) out[b] = p + bout[0];
}

extern "C" void kernel_launch(void* const* d_in, const int* in_sizes, int n_in,
                              void* d_out, int out_size, void* d_ws, size_t ws_size,
                              hipStream_t stream) {
    const float* input_seq = (const float*)d_in[0];
    const float* Kin       = (const float*)d_in[1];
    const float* R         = (const float*)d_in[2];
    const float* bias      = (const float*)d_in[3];
    const float* Wout      = (const float*)d_in[4];
    const float* bout      = (const float*)d_in[5];
    float* out = (float*)d_out;

    char* ws = (char*)d_ws;
    unsigned short* wpack = (unsigned short*)(ws);                    // 2,359,296 B
    unsigned int* hbuf    = (unsigned int*)(ws + 2359296);            // 1,048,576 B
    float* hlast          = (float*)(ws + 2359296 + 1048576);         //   524,288 B

    zero_tags<<<dim3(256), dim3(256), 0, stream>>>((u32x4*)hbuf);
    pack_w<<<dim3(576), dim3(256), 0, stream>>>(R, Kin, wpack);
    lstm_persist<<<dim3(128), dim3(512), 0, stream>>>(
        wpack, input_seq, bias, hbuf, hlast);
    out_kernel<<<dim3(256), dim3(64), 0, stream>>>(hlast, Wout, bout, out);
}